// Round 12
// baseline (374.592 us; speedup 1.0000x reference)
//
#include <hip/hip_runtime.h>
#include <stdint.h>

#define BB 2
#define SS 2048
#define MM 2048
#define NQ 16
#define NKV 4
#define HH 128
#define KVB 64

typedef __attribute__((ext_vector_type(4))) float f32x4;
typedef __attribute__((ext_vector_type(16))) float f32x16;
typedef _Float16 f16x8 __attribute__((ext_vector_type(8)));
typedef _Float16 f16x4 __attribute__((ext_vector_type(4)));
typedef _Float16 f16x2 __attribute__((ext_vector_type(2)));
typedef unsigned int uint4v __attribute__((ext_vector_type(4)));

__device__ __forceinline__ void gll16(const _Float16* g, _Float16* l) {
  __builtin_amdgcn_global_load_lds(
      (__attribute__((address_space(1))) void*)g,
      (__attribute__((address_space(3))) void*)l, 16, 0, 0);
}

__device__ __forceinline__ float fexp2(float x) {
#if __has_builtin(__builtin_amdgcn_exp2f)
  return __builtin_amdgcn_exp2f(x);   // raw v_exp_f32
#else
  float r;
  asm("v_exp_f32 %0, %1" : "=v"(r) : "v"(x));
  return r;
#endif
}

__device__ __forceinline__ unsigned int pkrtz(float a, float b) {
  return __builtin_bit_cast(unsigned int, __builtin_amdgcn_cvt_pkrtz(a, b));
}

// ---------------- fp32 -> fp16 convert (vectorized) ----------------
__global__ __launch_bounds__(256) void k_f32_to_f16(const float* __restrict__ in,
                                                    _Float16* __restrict__ out, int n4) {
  int i = blockIdx.x * 256 + threadIdx.x;
  if (i >= n4) return;
  float4 v = ((const float4*)in)[i];
  f16x4 o = { (_Float16)v.x, (_Float16)v.y, (_Float16)v.z, (_Float16)v.w };
  ((f16x4*)out)[i] = o;
}

// ------------- fused weight transposes: z selects {Wq,Wk,Wv,Wo} -------------
__global__ __launch_bounds__(256) void k_wtrans(
    const float* __restrict__ Wq, const float* __restrict__ Wk,
    const float* __restrict__ Wv, const float* __restrict__ Wo,
    _Float16* __restrict__ Wqkvt, _Float16* __restrict__ Wot) {
  const int z = blockIdx.z;
  if ((z == 1 || z == 2) && blockIdx.y >= 16) return;
  const float* in = (z == 0) ? Wq : (z == 1) ? Wk : (z == 2) ? Wv : Wo;
  _Float16* out = (z == 3) ? Wot : Wqkvt;
  const int N_in = (z == 1 || z == 2) ? 512 : 2048;
  const int n_off = (z == 1) ? 2048 : (z == 2) ? 2560 : 0;

  __shared__ float tile[32][33];
  const int k0 = blockIdx.x * 32;
  const int n0 = blockIdx.y * 32;
  const int tx = threadIdx.x & 31;
  const int ty = threadIdx.x >> 5;
  #pragma unroll
  for (int r = ty; r < 32; r += 8)
    tile[r][tx] = in[(size_t)(k0 + r) * N_in + n0 + tx];
  __syncthreads();
  #pragma unroll
  for (int r = ty; r < 32; r += 8)
    out[(size_t)(n0 + r + n_off) * 2048 + k0 + tx] = (_Float16)tile[tx][r];
}

// ------------- V transpose: qkv[b*S+s][2560+hv*128+h] -> VtG[(b*NKV+hv)*H+h][s] -------------
__global__ __launch_bounds__(256) void k_vtrans(const _Float16* __restrict__ qkv,
                                                _Float16* __restrict__ VtG) {
  __shared__ _Float16 tile[32][33];
  const int s0 = blockIdx.x * 32;
  const int z = blockIdx.y;
  const int h0 = (z & 3) * 32;
  const int bv = z >> 2;
  const int b = bv >> 2;
  const int hv = bv & 3;
  const int tx = threadIdx.x & 31;
  const int ty = threadIdx.x >> 5;
  #pragma unroll
  for (int r = ty; r < 32; r += 8)
    tile[r][tx] = qkv[(size_t)(b * SS + s0 + r) * 3072 + 2560 + hv * 128 + h0 + tx];
  __syncthreads();
  #pragma unroll
  for (int r = ty; r < 32; r += 8)
    VtG[((size_t)bv * HH + h0 + r) * SS + s0 + tx] = tile[tx][r];
}

// ============ 256xBN phase-split MFMA GEMM (round-7 state) ============
template <int FN, bool F16OUT>
__global__ __launch_bounds__(512, 2) void k_gemm256(
    const _Float16* __restrict__ A, const _Float16* __restrict__ Bt,
    void* __restrict__ Cout, int NT_M, int N, int K) {
  __shared__ _Float16 As[2][256 * 64];
  __shared__ _Float16 Bs[2][FN * 64 * 64];

  const int tid = threadIdx.x;
  const int w = tid >> 6;
  const int l = tid & 63;
  const int lr = l & 15;
  const int al4 = l >> 4;
  const int wr = w >> 2;
  const int wc = w & 3;
  const int swz = (lr & 7) << 4;

  const int nwg = gridDim.x;
  const int bid = blockIdx.x;
  const int sbid = (bid & 7) * (nwg >> 3) + (bid >> 3);
  const int bm = (sbid % NT_M) * 256;
  const int bn = (sbid / NT_M) * (FN * 64);
  const int KT = K >> 6;

  const int srow = tid >> 3;
  const int sch = (tid & 7) ^ (srow & 7);
  const _Float16* aSrc = A + (size_t)(bm + srow) * K + sch * 8;
  const _Float16* bSrc = Bt + (size_t)(bn + srow) * K + sch * 8;

  auto stA = [&](int buf, int r, int kt) {
    gll16(aSrc + (size_t)(r * 64) * K + kt * 64, &As[buf][r * 4096 + w * 512]);
  };
  auto stB = [&](int buf, int r, int kt) {
    gll16(bSrc + (size_t)(r * 64) * K + kt * 64, &Bs[buf][r * 4096 + w * 512]);
  };

  f32x4 acc[8][FN] = {};

  stA(0, 0, 0); stA(0, 1, 0); stA(0, 2, 0); stA(0, 3, 0);
  stB(0, 0, 0); stB(0, 1, 0);
  if (FN == 3) stB(0, 2, 0);
  if (KT > 1) {
    stA(1, 0, 1); stA(1, 2, 1); stB(1, 0, 1); stB(1, 1, 1);
    asm volatile("s_waitcnt vmcnt(4)" ::: "memory");
  } else {
    asm volatile("s_waitcnt vmcnt(0)" ::: "memory");
  }
  __builtin_amdgcn_s_barrier();

  for (int t = 0; t < KT; ++t) {
    const int cb = t & 1;
    const char* Ab = (const char*)&As[cb][0];
    const char* Bb = (const char*)&Bs[cb][0];
    f16x8 bF[FN][2];
    #pragma unroll
    for (int ph = 0; ph < 4; ++ph) {
      f16x8 aF[2][2];
      #pragma unroll
      for (int fm = 0; fm < 2; ++fm)
        #pragma unroll
        for (int ks = 0; ks < 2; ++ks) {
          const int row = wr * 128 + (ph * 2 + fm) * 16 + lr;
          aF[fm][ks] = *(const f16x8*)(Ab + row * 128 + (((ks * 4 + al4) * 16) ^ swz));
        }
      if (ph == 0) {
        #pragma unroll
        for (int fn = 0; fn < FN; ++fn)
          #pragma unroll
          for (int ks = 0; ks < 2; ++ks) {
            const int col = wc * (FN * 16) + fn * 16 + lr;
            bF[fn][ks] = *(const f16x8*)(Bb + col * 128 + (((ks * 4 + al4) * 16) ^ swz));
          }
      }
      if (ph == 0 && FN == 3 && t + 1 < KT) stB(cb ^ 1, 2, t + 1);
      if (ph == 1 && t + 1 < KT) { stA(cb ^ 1, 1, t + 1); stA(cb ^ 1, 3, t + 1); }
      if (ph == 2 && t + 2 < KT) { stA(cb, 0, t + 2); stA(cb, 2, t + 2); }
      if (ph == 3 && t + 2 < KT) { stB(cb, 0, t + 2); stB(cb, 1, t + 2); }
      __builtin_amdgcn_s_barrier();
      asm volatile("s_waitcnt lgkmcnt(0)" ::: "memory");
      __builtin_amdgcn_sched_barrier(0);
      __builtin_amdgcn_s_setprio(1);
      #pragma unroll
      for (int fm = 0; fm < 2; ++fm)
        #pragma unroll
        for (int fn = 0; fn < FN; ++fn)
          #pragma unroll
          for (int ks = 0; ks < 2; ++ks)
            acc[ph * 2 + fm][fn] = __builtin_amdgcn_mfma_f32_16x16x32_f16(
                aF[fm][ks], bF[fn][ks], acc[ph * 2 + fm][fn], 0, 0, 0);
      __builtin_amdgcn_s_setprio(0);
      __builtin_amdgcn_sched_barrier(0);
      if (ph < 3) {
        __builtin_amdgcn_s_barrier();
      } else {
        if (t + 2 < KT) asm volatile("s_waitcnt vmcnt(4)" ::: "memory");
        else            asm volatile("s_waitcnt vmcnt(0)" ::: "memory");
        __builtin_amdgcn_s_barrier();
      }
    }
  }

  #pragma unroll
  for (int fm = 0; fm < 8; ++fm) {
    #pragma unroll
    for (int i = 0; i < 4; ++i) {
      const int row = bm + wr * 128 + fm * 16 + al4 * 4 + i;
      #pragma unroll
      for (int fn = 0; fn < FN; ++fn) {
        const int col = bn + wc * (FN * 16) + fn * 16 + lr;
        if (F16OUT)
          ((_Float16*)Cout)[(size_t)row * N + col] = (_Float16)acc[fm][fn][i];
        else
          ((float*)Cout)[(size_t)row * N + col] = acc[fm][fn][i];
      }
    }
  }
}

// ---------------- fused RMSNorm + RoPE + scatter (Q, K only) ----------------
__global__ __launch_bounds__(256) void k_normrope(
    const _Float16* __restrict__ qkv,
    const float* __restrict__ q_scale, const float* __restrict__ k_scale,
    _Float16* __restrict__ Qr, _Float16* __restrict__ Kr) {
  const int row = blockIdx.x;
  const int b = row >> 11;
  const int s = row & 2047;
  const int hh = blockIdx.y * 4 + (threadIdx.x >> 6);
  const int l = threadIdx.x & 63;
  const _Float16* src = qkv + (size_t)row * 3072 + hh * 128 + l * 2;
  float x0 = (float)src[0];
  float x1 = (float)src[1];
  float ssum = x0 * x0 + x1 * x1;
  #pragma unroll
  for (int d = 1; d < 64; d <<= 1) ssum += __shfl_xor(ssum, d);
  const float rstd = rsqrtf(ssum * (1.f / 128.f) + 1e-6f);
  const float* scl = (hh < 16) ? q_scale : k_scale;
  x0 *= rstd * scl[2 * l];
  x1 *= rstd * scl[2 * l + 1];
  const float y0 = __shfl_xor(x0, 32);
  const float y1 = __shfl_xor(x1, 32);
  const int j0 = (2 * l) & 63;
  const float kLog = 0.20762050593046014f;
  const float f0 = (float)s * exp2f(-(float)j0 * kLog);
  const float f1 = (float)s * exp2f(-(float)(j0 + 1) * kLog);
  const float c0 = cosf(f0), s0 = sinf(f0);
  const float c1 = cosf(f1), s1 = sinf(f1);
  float r0, r1;
  if (l < 32) { r0 = x0 * c0 - y0 * s0; r1 = x1 * c1 - y1 * s1; }
  else        { r0 = x0 * c0 + y0 * s0; r1 = x1 * c1 + y1 * s1; }
  if (hh < 16) {
    _Float16* dst = Qr + ((size_t)(b * NQ + hh) * SS + s) * HH + 2 * l;
    dst[0] = (_Float16)r0; dst[1] = (_Float16)r1;
  } else {
    _Float16* dst = Kr + ((size_t)(b * NKV + (hh - 16)) * SS + s) * HH + 2 * l;
    dst[0] = (_Float16)r0; dst[1] = (_Float16)r1;
  }
}

// ---- causal GQA flash attention: 4 waves x 64 q-rows (K/V frags shared across q-halves) ----
// Strips s=0..7 (256 q). s>=4 split into kv-halves -> 12 tasks/bu, 384 blocks, all resident
// at 2 blocks/CU. Fixed-max softmax => disjoint-kv partials add; k_fin combines.
// enc = s*4 + heavy*2 + half, longest-first.
__device__ const unsigned char g_tasks[12] = {
  30, 31, 12, 26, 27, 22, 23, 8, 18, 19, 4, 0
};

__global__ __launch_bounds__(256, 2) void k_attn(
    const _Float16* __restrict__ Qr, const _Float16* __restrict__ Kr,
    const _Float16* __restrict__ VtG,
    const float* __restrict__ qs, const float* __restrict__ ks,
    float* __restrict__ PartA, float* __restrict__ PartB,
    float* __restrict__ psA, float* __restrict__ psB,
    _Float16* __restrict__ Ao) {
  __shared__ _Float16 Ks[2][KVB * 128];   // 16KB/buf, XOR-swizzled content
  __shared__ _Float16 Vs[2][128 * KVB];   // 16KB/buf

  const int tid = threadIdx.x;
  const int w = tid >> 6;
  const int l = tid & 63;
  const int l31 = l & 31;
  const int hi = l >> 5;
  const int sw7 = (l31 & 7) << 4;
  const int bu = blockIdx.x;
  const int b = bu >> 4, u = bu & 15;
  const int kvh = u >> 2;

  const int task = g_tasks[blockIdx.y];
  const int s = task >> 2;               // strip (256 q-rows)
  const int heavy = (task >> 1) & 1;
  const int half = task & 1;
  const int q0 = s * 256;
  const int halfLen = 2 * (s + 1);
  const int t0 = heavy ? half * halfLen : 0;
  const int t1 = heavy ? t0 + halfLen : 4 * (s + 1);

  float ma = fmaxf(fabsf(qs[l]), fabsf(qs[l + 64]));
  float mb = fmaxf(fabsf(ks[l]), fabsf(ks[l + 64]));
  #pragma unroll
  for (int d = 1; d < 64; d <<= 1) {
    ma = fmaxf(ma, __shfl_xor(ma, d));
    mb = fmaxf(mb, __shfl_xor(mb, d));
  }
  const float M2 = 1.4426950408889634f * ma * mb;
  const float K2 = 0.12752982260735795f; // log2(e)/sqrt(128)

  const _Float16* Kbase = Kr + (size_t)(b * NKV + kvh) * SS * HH;
  const _Float16* Vbase = VtG + (size_t)(b * NKV + kvh) * HH * SS;

  const int qwb = q0 + w * 64;           // wave's first q-row (64 rows per wave)

  // Q fragments for both q-halves (B-operand of swapped QK^T)
  f16x8 qfA[8], qfB[8];
  {
    const _Float16* qpA = Qr + ((size_t)(b * NQ + u) * SS + qwb + l31) * HH + hi * 8;
    const _Float16* qpB = qpA + (size_t)32 * HH;
    #pragma unroll
    for (int hs = 0; hs < 8; hs++) {
      qfA[hs] = *(const f16x8*)(qpA + hs * 16);
      qfA[hs] *= (_Float16)K2;
      qfB[hs] = *(const f16x8*)(qpB + hs * 16);
      qfB[hs] *= (_Float16)K2;
    }
  }

  f32x16 accA0 = {}, accA1 = {}, accA2 = {}, accA3 = {};
  f32x16 accB0 = {}, accB1 = {}, accB2 = {}, accB3 = {};
  float psumA = 0.f, psumB = 0.f;

  auto stage = [&](int buf, int t) {
    const int kv0 = t * KVB;
    #pragma unroll
    for (int it = 0; it < 4; it++) {
      const int n = it * 256 + tid;
      {  // K tile: 64 rows x 256B (16 chunks/row)
        const int row = n >> 4, c = n & 15;
        const int cs = c ^ (row & 7);
        gll16(Kbase + (size_t)(kv0 + row) * HH + cs * 8,
              &Ks[buf][(size_t)(it * 256 + w * 64) * 8]);
      }
      {  // V^T tile: 128 rows x 128B (8 chunks/row)
        const int row = n >> 3, c = n & 7;
        const int cs = c ^ (row & 7);
        gll16(Vbase + (size_t)row * SS + kv0 + cs * 8,
              &Vs[buf][(size_t)(it * 256 + w * 64) * 8]);
      }
    }
  };

  int buf = 0;
  stage(0, t0);
  __syncthreads();

  const int qlaneA = qwb + l31;
  const int qlaneB = qwb + 32 + l31;

  for (int t = t0; t < t1; t++) {
    if (t + 1 < t1) stage(buf ^ 1, t + 1);
    const int kv0 = t * KVB;
    if (kv0 <= qwb + 63) {
      const char* Kb = (const char*)&Ks[buf][0];
      const char* Vb = (const char*)&Vs[buf][0];
      const bool maskA = (kv0 + 63 > qwb);
      const bool maskB = (kv0 + 63 > qwb + 32);

      f16x8 paA[4], paB[4];

      // ---- two K-row phases: kph=0 -> k-rows 0..31, kph=1 -> 32..63 ----
      #pragma unroll
      for (int kph = 0; kph < 2; kph++) {
        f32x16 SA = {}, SB = {};
        __builtin_amdgcn_s_setprio(1);
        #pragma unroll
        for (int hs = 0; hs < 8; hs++) {
          const int ch = hs * 2 + hi;
          f16x8 kf = *(const f16x8*)(Kb + (kph * 32 + l31) * 256 + ((ch << 4) ^ sw7));
          SA = __builtin_amdgcn_mfma_f32_32x32x16_f16(kf, qfA[hs], SA, 0, 0, 0);
          SB = __builtin_amdgcn_mfma_f32_32x32x16_f16(kf, qfB[hs], SB, 0, 0, 0);
        }
        __builtin_amdgcn_s_setprio(0);

        float pA[16], pB[16];
        #pragma unroll
        for (int r = 0; r < 16; r++) {
          const int cr = (r & 3) + 8 * (r >> 2) + 4 * hi;  // k-row within 32
          const int ka = kv0 + kph * 32 + cr;
          float eA = fexp2(SA[r] - M2);
          float eB = fexp2(SB[r] - M2);
          if (maskA && ka > qlaneA) eA = 0.f;
          if (maskB && ka > qlaneB) eB = 0.f;
          pA[r] = eA; pB[r] = eB;
          psumA += eA; psumB += eB;
        }

        unsigned int pkA[2][4], pkB[2][4];
        #pragma unroll
        for (int g = 0; g < 4; g++) {
          pkA[0][g] = pkrtz(pA[2 * g], pA[2 * g + 1]);
          pkA[1][g] = pkrtz(pA[8 + 2 * g], pA[9 + 2 * g]);
          pkB[0][g] = pkrtz(pB[2 * g], pB[2 * g + 1]);
          pkB[1][g] = pkrtz(pB[8 + 2 * g], pB[9 + 2 * g]);
        }
        #pragma unroll
        for (int kk = 0; kk < 2; kk++) {
          {
            unsigned int a0 = pkA[kk][0], a1 = pkA[kk][1], a2 = pkA[kk][2], a3 = pkA[kk][3];
            unsigned int x0 = (unsigned int)__shfl_xor((int)a0, 32);
            unsigned int x1 = (unsigned int)__shfl_xor((int)a1, 32);
            unsigned int x2 = (unsigned int)__shfl_xor((int)a2, 32);
            unsigned int x3 = (unsigned int)__shfl_xor((int)a3, 32);
            uint4v dv;
            dv.x = hi ? x2 : a0;
            dv.y = hi ? x3 : a1;
            dv.z = hi ? a2 : x0;
            dv.w = hi ? a3 : x1;
            paA[kph * 2 + kk] = __builtin_bit_cast(f16x8, dv);
          }
          {
            unsigned int a0 = pkB[kk][0], a1 = pkB[kk][1], a2 = pkB[kk][2], a3 = pkB[kk][3];
            unsigned int x0 = (unsigned int)__shfl_xor((int)a0, 32);
            unsigned int x1 = (unsigned int)__shfl_xor((int)a1, 32);
            unsigned int x2 = (unsigned int)__shfl_xor((int)a2, 32);
            unsigned int x3 = (unsigned int)__shfl_xor((int)a3, 32);
            uint4v dv;
            dv.x = hi ? x2 : a0;
            dv.y = hi ? x3 : a1;
            dv.z = hi ? a2 : x0;
            dv.w = hi ? a3 : x1;
            paB[kph * 2 + kk] = __builtin_bit_cast(f16x8, dv);
          }
        }
      }

      // ---- PV: V fragment loaded once, feeds both q-halves ----
      __builtin_amdgcn_s_setprio(1);
      #pragma unroll
      for (int ksx = 0; ksx < 4; ksx++) {
        const int ch = ksx * 2 + hi;
        {
          f16x8 v0 = *(const f16x8*)(Vb + (0 * 32 + l31) * 128 + ((ch << 4) ^ sw7));
          accA0 = __builtin_amdgcn_mfma_f32_32x32x16_f16(paA[ksx], v0, accA0, 0, 0, 0);
          accB0 = __builtin_amdgcn_mfma_f32_32x32x16_f16(paB[ksx], v0, accB0, 0, 0, 0);
        }
        {
          f16x8 v1 = *(const f16x8*)(Vb + (1 * 32 + l31) * 128 + ((ch << 4) ^ sw7));
          accA1 = __builtin_amdgcn_mfma_f32_32x32x16_f16(paA[ksx], v1, accA1, 0, 0, 0);
          accB1 = __builtin_amdgcn_mfma_f32_32x32x16_f16(paB[ksx], v1, accB1, 0, 0, 0);
        }
        {
          f16x8 v2 = *(const f16x8*)(Vb + (2 * 32 + l31) * 128 + ((ch << 4) ^ sw7));
          accA2 = __builtin_amdgcn_mfma_f32_32x32x16_f16(paA[ksx], v2, accA2, 0, 0, 0);
          accB2 = __builtin_amdgcn_mfma_f32_32x32x16_f16(paB[ksx], v2, accB2, 0, 0, 0);
        }
        {
          f16x8 v3 = *(const f16x8*)(Vb + (3 * 32 + l31) * 128 + ((ch << 4) ^ sw7));
          accA3 = __builtin_amdgcn_mfma_f32_32x32x16_f16(paA[ksx], v3, accA3, 0, 0, 0);
          accB3 = __builtin_amdgcn_mfma_f32_32x32x16_f16(paB[ksx], v3, accB3, 0, 0, 0);
        }
      }
      __builtin_amdgcn_s_setprio(0);
    }
    __syncthreads();
    buf ^= 1;
  }

  const float totA = psumA + __shfl_xor(psumA, 32);
  const float totB = psumB + __shfl_xor(psumB, 32);
  if (heavy) {
    const int slot = bu * 4 + (s - 4);          // 128 slots of 256q x 128h
    float* pPart = (half ? PartB : PartA) + (size_t)slot * 32768;
    float* sPart = (half ? psB : psA) + slot * 256;
    if (hi == 0) {
      sPart[w * 64 + l31] = totA;
      sPart[w * 64 + 32 + l31] = totB;
    }
    #pragma unroll
    for (int r = 0; r < 16; r++) {
      const int cr = (r & 3) + 8 * (r >> 2) + 4 * hi;
      {
        float* dst = pPart + (size_t)(w * 64 + cr) * 128 + l31;
        dst[0]  = accA0[r];
        dst[32] = accA1[r];
        dst[64] = accA2[r];
        dst[96] = accA3[r];
      }
      {
        float* dst = pPart + (size_t)(w * 64 + 32 + cr) * 128 + l31;
        dst[0]  = accB0[r];
        dst[32] = accB1[r];
        dst[64] = accB2[r];
        dst[96] = accB3[r];
      }
    }
  } else {
    const float invA = 1.f / totA;
    const float invB = 1.f / totB;
    #pragma unroll
    for (int r = 0; r < 16; r++) {
      const int cr = (r & 3) + 8 * (r >> 2) + 4 * hi;
      {
        const float ivr = __shfl(invA, cr);
        _Float16* dst = Ao + ((size_t)(b * SS + qwb + cr)) * MM + u * HH + l31;
        dst[0]  = (_Float16)(accA0[r] * ivr);
        dst[32] = (_Float16)(accA1[r] * ivr);
        dst[64] = (_Float16)(accA2[r] * ivr);
        dst[96] = (_Float16)(accA3[r] * ivr);
      }
      {
        const float ivr = __shfl(invB, cr);
        _Float16* dst = Ao + ((size_t)(b * SS + qwb + 32 + cr)) * MM + u * HH + l31;
        dst[0]  = (_Float16)(accB0[r] * ivr);
        dst[32] = (_Float16)(accB1[r] * ivr);
        dst[64] = (_Float16)(accB2[r] * ivr);
        dst[96] = (_Float16)(accB3[r] * ivr);
      }
    }
  }
}

// ---------------- combine heavy-strip partials -> Ao f16 ----------------
__global__ __launch_bounds__(256) void k_fin(
    const float* __restrict__ PartA, const float* __restrict__ PartB,
    const float* __restrict__ psA, const float* __restrict__ psB,
    _Float16* __restrict__ Ao) {
  const int bx = blockIdx.x;               // 256 blocks = 128 slots x 2 q-halves
  const int slot = bx >> 1, qh = bx & 1;
  const int bu = slot >> 2, st = slot & 3;
  const int b = bu >> 4, u = bu & 15;
  const int q0 = (st + 4) * 256 + qh * 128;
  const float* pa = PartA + (size_t)slot * 32768 + qh * 16384;
  const float* pb = PartB + (size_t)slot * 32768 + qh * 16384;
  const float* sa = psA + slot * 256 + qh * 128;
  const float* sb = psB + slot * 256 + qh * 128;
  #pragma unroll
  for (int it = 0; it < 16; it++) {
    const int unit = it * 256 + threadIdx.x;
    const int qr = unit >> 5, cg = unit & 31;
    const float inv = 1.f / (sa[qr] + sb[qr]);
    f32x4 va = *(const f32x4*)(pa + qr * 128 + cg * 4);
    f32x4 vb = *(const f32x4*)(pb + qr * 128 + cg * 4);
    f16x4 o = { (_Float16)((va[0] + vb[0]) * inv), (_Float16)((va[1] + vb[1]) * inv),
                (_Float16)((va[2] + vb[2]) * inv), (_Float16)((va[3] + vb[3]) * inv) };
    *(f16x4*)(Ao + ((size_t)(b * SS + q0 + qr)) * MM + u * HH + cg * 4) = o;
  }
}

// ---------------- launcher ----------------
extern "C" void kernel_launch(void* const* d_in, const int* in_sizes, int n_in,
                              void* d_out, int out_size, void* d_ws, size_t ws_size,
                              hipStream_t stream) {
  const float* hidden = (const float*)d_in[0];
  const float* Wq = (const float*)d_in[2];
  const float* Wk = (const float*)d_in[3];
  const float* Wv = (const float*)d_in[4];
  const float* Wo = (const float*)d_in[5];
  const float* q_scale = (const float*)d_in[6];
  const float* k_scale = (const float*)d_in[7];

  char* ws = (char*)d_ws;
  _Float16* Xb    = (_Float16*)(ws);               // 4096x2048      16.78 MB (dead after GEMM1)
  _Float16* Wqkvt = (_Float16*)(ws + 16777216);    // 3072x2048      12.58 MB
  _Float16* Wot   = (_Float16*)(ws + 29360128);    // 2048x2048       8.39 MB
  _Float16* qkv   = (_Float16*)(ws + 37748736);    // 4096x3072      25.17 MB (dead after vtrans)
  _Float16* Qr    = (_Float16*)(ws + 62914560);    // 2x16x2048x128  16.78 MB
  _Float16* Kr    = (_Float16*)(ws + 79691776);    // 2x4x2048x128    4.19 MB
  _Float16* VtG   = (_Float16*)(ws + 83886080);    // 2x4x128x2048    4.19 MB
  _Float16* Ao    = (_Float16*)(ws + 88080384);    // 4096x2048      16.78 MB
  // scratch reuse (dead regions): 128 slots x 32768 f32 = 16.78 MB each
  float*    PartB = (float*)(ws);                  // over Xb
  float*    PartA = (float*)(ws + 37748736);       // over qkv
  float*    psA   = (float*)(ws + 54525952);       // 128 KB
  float*    psB   = (float*)(ws + 54657024);       // 128 KB

  k_f32_to_f16<<<dim3(8192), dim3(256), 0, stream>>>(hidden, Xb, 2097152);
  k_wtrans<<<dim3(64, 64, 4), dim3(256), 0, stream>>>(Wq, Wk, Wv, Wo, Wqkvt, Wot);
  k_gemm256<3, true><<<dim3(256), dim3(512), 0, stream>>>(Xb, Wqkvt, (void*)qkv, 16, 3072, 2048);
  k_normrope<<<dim3(4096, 5), dim3(256), 0, stream>>>(qkv, q_scale, k_scale, Qr, Kr);
  k_vtrans<<<dim3(64, 32), dim3(256), 0, stream>>>(qkv, VtG);
  k_attn<<<dim3(32, 12), dim3(256), 0, stream>>>(Qr, Kr, VtG, q_scale, k_scale,
                                                 PartA, PartB, psA, psB, Ao);
  k_fin<<<dim3(256), dim3(256), 0, stream>>>(PartA, PartB, psA, psB, Ao);
  k_gemm256<2, false><<<dim3(256), dim3(512), 0, stream>>>(Ao, Wot, d_out, 16, 2048, 2048);
}

// Round 13
// 217.123 us; speedup vs baseline: 1.7253x; 1.7253x over previous
//
#include <hip/hip_runtime.h>
#include <stdint.h>

#define BB 2
#define SS 2048
#define MM 2048
#define NQ 16
#define NKV 4
#define HH 128
#define KVB 64

typedef __attribute__((ext_vector_type(4))) float f32x4;
typedef __attribute__((ext_vector_type(16))) float f32x16;
typedef _Float16 f16x8 __attribute__((ext_vector_type(8)));
typedef _Float16 f16x4 __attribute__((ext_vector_type(4)));
typedef _Float16 f16x2 __attribute__((ext_vector_type(2)));
typedef unsigned int uint4v __attribute__((ext_vector_type(4)));

__device__ __forceinline__ void gll16(const _Float16* g, _Float16* l) {
  __builtin_amdgcn_global_load_lds(
      (__attribute__((address_space(1))) void*)g,
      (__attribute__((address_space(3))) void*)l, 16, 0, 0);
}

__device__ __forceinline__ float fexp2(float x) {
#if __has_builtin(__builtin_amdgcn_exp2f)
  return __builtin_amdgcn_exp2f(x);   // raw v_exp_f32
#else
  float r;
  asm("v_exp_f32 %0, %1" : "=v"(r) : "v"(x));
  return r;
#endif
}

__device__ __forceinline__ unsigned int pkrtz(float a, float b) {
  return __builtin_bit_cast(unsigned int, __builtin_amdgcn_cvt_pkrtz(a, b));
}

// ---------------- fp32 -> fp16 convert (vectorized) ----------------
__global__ __launch_bounds__(256) void k_f32_to_f16(const float* __restrict__ in,
                                                    _Float16* __restrict__ out, int n4) {
  int i = blockIdx.x * 256 + threadIdx.x;
  if (i >= n4) return;
  float4 v = ((const float4*)in)[i];
  f16x4 o = { (_Float16)v.x, (_Float16)v.y, (_Float16)v.z, (_Float16)v.w };
  ((f16x4*)out)[i] = o;
}

// ------------- fused weight transposes: z selects {Wq,Wk,Wv,Wo} -------------
__global__ __launch_bounds__(256) void k_wtrans(
    const float* __restrict__ Wq, const float* __restrict__ Wk,
    const float* __restrict__ Wv, const float* __restrict__ Wo,
    _Float16* __restrict__ Wqkvt, _Float16* __restrict__ Wot) {
  const int z = blockIdx.z;
  if ((z == 1 || z == 2) && blockIdx.y >= 16) return;
  const float* in = (z == 0) ? Wq : (z == 1) ? Wk : (z == 2) ? Wv : Wo;
  _Float16* out = (z == 3) ? Wot : Wqkvt;
  const int N_in = (z == 1 || z == 2) ? 512 : 2048;
  const int n_off = (z == 1) ? 2048 : (z == 2) ? 2560 : 0;

  __shared__ float tile[32][33];
  const int k0 = blockIdx.x * 32;
  const int n0 = blockIdx.y * 32;
  const int tx = threadIdx.x & 31;
  const int ty = threadIdx.x >> 5;
  #pragma unroll
  for (int r = ty; r < 32; r += 8)
    tile[r][tx] = in[(size_t)(k0 + r) * N_in + n0 + tx];
  __syncthreads();
  #pragma unroll
  for (int r = ty; r < 32; r += 8)
    out[(size_t)(n0 + r + n_off) * 2048 + k0 + tx] = (_Float16)tile[tx][r];
}

// ------------- V transpose: qkv[b*S+s][2560+hv*128+h] -> VtG[(b*NKV+hv)*H+h][s] -------------
__global__ __launch_bounds__(256) void k_vtrans(const _Float16* __restrict__ qkv,
                                                _Float16* __restrict__ VtG) {
  __shared__ _Float16 tile[32][33];
  const int s0 = blockIdx.x * 32;
  const int z = blockIdx.y;
  const int h0 = (z & 3) * 32;
  const int bv = z >> 2;
  const int b = bv >> 2;
  const int hv = bv & 3;
  const int tx = threadIdx.x & 31;
  const int ty = threadIdx.x >> 5;
  #pragma unroll
  for (int r = ty; r < 32; r += 8)
    tile[r][tx] = qkv[(size_t)(b * SS + s0 + r) * 3072 + 2560 + hv * 128 + h0 + tx];
  __syncthreads();
  #pragma unroll
  for (int r = ty; r < 32; r += 8)
    VtG[((size_t)bv * HH + h0 + r) * SS + s0 + tx] = tile[tx][r];
}

// ============ 256xBN MFMA GEMM, 2 merged phases per K-tile ============
// 8 waves (2M x 4N), BK=64, dbuf LDS, T2 swizzle, read-once fragments (B held in regs),
// counted vmcnt(4), T5 setprio, T1 XCD swizzle. Barriers per tile: 4 (was 8).
template <int FN, bool F16OUT>
__global__ __launch_bounds__(512, 2) void k_gemm256(
    const _Float16* __restrict__ A, const _Float16* __restrict__ Bt,
    void* __restrict__ Cout, int NT_M, int N, int K) {
  __shared__ _Float16 As[2][256 * 64];
  __shared__ _Float16 Bs[2][FN * 64 * 64];

  const int tid = threadIdx.x;
  const int w = tid >> 6;
  const int l = tid & 63;
  const int lr = l & 15;
  const int al4 = l >> 4;
  const int wr = w >> 2;
  const int wc = w & 3;
  const int swz = (lr & 7) << 4;

  const int nwg = gridDim.x;
  const int bid = blockIdx.x;
  const int sbid = (bid & 7) * (nwg >> 3) + (bid >> 3);
  const int bm = (sbid % NT_M) * 256;
  const int bn = (sbid / NT_M) * (FN * 64);
  const int KT = K >> 6;

  const int srow = tid >> 3;
  const int sch = (tid & 7) ^ (srow & 7);
  const _Float16* aSrc = A + (size_t)(bm + srow) * K + sch * 8;
  const _Float16* bSrc = Bt + (size_t)(bn + srow) * K + sch * 8;

  auto stA = [&](int buf, int r, int kt) {
    gll16(aSrc + (size_t)(r * 64) * K + kt * 64, &As[buf][r * 4096 + w * 512]);
  };
  auto stB = [&](int buf, int r, int kt) {
    gll16(bSrc + (size_t)(r * 64) * K + kt * 64, &Bs[buf][r * 4096 + w * 512]);
  };

  f32x4 acc[8][FN] = {};

  // prologue: tile0 fully + tile1's A0,A2,B0,B1
  stA(0, 0, 0); stA(0, 1, 0); stA(0, 2, 0); stA(0, 3, 0);
  stB(0, 0, 0); stB(0, 1, 0);
  if (FN == 3) stB(0, 2, 0);
  if (KT > 1) {
    stA(1, 0, 1); stA(1, 2, 1); stB(1, 0, 1); stB(1, 1, 1);
    asm volatile("s_waitcnt vmcnt(4)" ::: "memory");
  } else {
    asm volatile("s_waitcnt vmcnt(0)" ::: "memory");
  }
  __builtin_amdgcn_s_barrier();

  for (int t = 0; t < KT; ++t) {
    const int cb = t & 1;
    const char* Ab = (const char*)&As[cb][0];
    const char* Bb = (const char*)&Bs[cb][0];
    f16x8 bF[FN][2];
    #pragma unroll
    for (int ph = 0; ph < 2; ++ph) {
      // ---- ds-read this phase's 4 A fragments (8 x b128, once each) ----
      f16x8 aF[4][2];
      #pragma unroll
      for (int fm = 0; fm < 4; ++fm)
        #pragma unroll
        for (int ks = 0; ks < 2; ++ks) {
          const int row = wr * 128 + (ph * 4 + fm) * 16 + lr;
          aF[fm][ks] = *(const f16x8*)(Ab + row * 128 + (((ks * 4 + al4) * 16) ^ swz));
        }
      if (ph == 0) {  // all B fragments once; held in registers across phases
        #pragma unroll
        for (int fn = 0; fn < FN; ++fn)
          #pragma unroll
          for (int ks = 0; ks < 2; ++ks) {
            const int col = wc * (FN * 16) + fn * 16 + lr;
            bF[fn][ks] = *(const f16x8*)(Bb + col * 128 + (((ks * 4 + al4) * 16) ^ swz));
          }
      }
      // ---- staging (targets' last readers completed >=1 barrier ago) ----
      if (ph == 0 && t + 1 < KT) {
        if (FN == 3) stB(cb ^ 1, 2, t + 1);
        stA(cb ^ 1, 1, t + 1); stA(cb ^ 1, 3, t + 1);
      }
      if (ph == 1 && t + 2 < KT) {
        stA(cb, 0, t + 2); stA(cb, 2, t + 2);
        stB(cb, 0, t + 2); stB(cb, 1, t + 2);
      }
      __builtin_amdgcn_s_barrier();
      asm volatile("s_waitcnt lgkmcnt(0)" ::: "memory");
      __builtin_amdgcn_sched_barrier(0);
      __builtin_amdgcn_s_setprio(1);
      #pragma unroll
      for (int fm = 0; fm < 4; ++fm)
        #pragma unroll
        for (int fn = 0; fn < FN; ++fn)
          #pragma unroll
          for (int ks = 0; ks < 2; ++ks)
            acc[ph * 4 + fm][fn] = __builtin_amdgcn_mfma_f32_16x16x32_f16(
                aF[fm][ks], bF[fn][ks], acc[ph * 4 + fm][fn], 0, 0, 0);
      __builtin_amdgcn_s_setprio(0);
      __builtin_amdgcn_sched_barrier(0);
      if (ph == 0) {
        __builtin_amdgcn_s_barrier();
      } else {
        // counted drain: keep t+2's 4 rounds in flight, drain t+1's
        if (t + 2 < KT) asm volatile("s_waitcnt vmcnt(4)" ::: "memory");
        else            asm volatile("s_waitcnt vmcnt(0)" ::: "memory");
        __builtin_amdgcn_s_barrier();
      }
    }
  }

  // ---- epilogue ----
  #pragma unroll
  for (int fm = 0; fm < 8; ++fm) {
    #pragma unroll
    for (int i = 0; i < 4; ++i) {
      const int row = bm + wr * 128 + fm * 16 + al4 * 4 + i;
      #pragma unroll
      for (int fn = 0; fn < FN; ++fn) {
        const int col = bn + wc * (FN * 16) + fn * 16 + lr;
        if (F16OUT)
          ((_Float16*)Cout)[(size_t)row * N + col] = (_Float16)acc[fm][fn][i];
        else
          ((float*)Cout)[(size_t)row * N + col] = acc[fm][fn][i];
      }
    }
  }
}

// ---------------- fused RMSNorm + RoPE + scatter (Q, K only) ----------------
__global__ __launch_bounds__(256) void k_normrope(
    const _Float16* __restrict__ qkv,
    const float* __restrict__ q_scale, const float* __restrict__ k_scale,
    _Float16* __restrict__ Qr, _Float16* __restrict__ Kr) {
  const int row = blockIdx.x;
  const int b = row >> 11;
  const int s = row & 2047;
  const int hh = blockIdx.y * 4 + (threadIdx.x >> 6);
  const int l = threadIdx.x & 63;
  const _Float16* src = qkv + (size_t)row * 3072 + hh * 128 + l * 2;
  float x0 = (float)src[0];
  float x1 = (float)src[1];
  float ssum = x0 * x0 + x1 * x1;
  #pragma unroll
  for (int d = 1; d < 64; d <<= 1) ssum += __shfl_xor(ssum, d);
  const float rstd = rsqrtf(ssum * (1.f / 128.f) + 1e-6f);
  const float* scl = (hh < 16) ? q_scale : k_scale;
  x0 *= rstd * scl[2 * l];
  x1 *= rstd * scl[2 * l + 1];
  const float y0 = __shfl_xor(x0, 32);
  const float y1 = __shfl_xor(x1, 32);
  const int j0 = (2 * l) & 63;
  const float kLog = 0.20762050593046014f;
  const float f0 = (float)s * exp2f(-(float)j0 * kLog);
  const float f1 = (float)s * exp2f(-(float)(j0 + 1) * kLog);
  const float c0 = cosf(f0), s0 = sinf(f0);
  const float c1 = cosf(f1), s1 = sinf(f1);
  float r0, r1;
  if (l < 32) { r0 = x0 * c0 - y0 * s0; r1 = x1 * c1 - y1 * s1; }
  else        { r0 = x0 * c0 + y0 * s0; r1 = x1 * c1 + y1 * s1; }
  if (hh < 16) {
    _Float16* dst = Qr + ((size_t)(b * NQ + hh) * SS + s) * HH + 2 * l;
    dst[0] = (_Float16)r0; dst[1] = (_Float16)r1;
  } else {
    _Float16* dst = Kr + ((size_t)(b * NKV + (hh - 16)) * SS + s) * HH + 2 * l;
    dst[0] = (_Float16)r0; dst[1] = (_Float16)r1;
  }
}

// ---------------- causal GQA flash attention: single-buffer, 3 blocks/CU (round-11) ----
__device__ const unsigned char g_tasks[24] = {
  61, 63, 28,
  57, 59, 53, 55, 24,
  49, 51, 45, 47, 20,
  41, 43, 37, 39, 16,
  33, 35, 12,
  8, 4, 0
};

__global__ __launch_bounds__(256, 3) void k_attn(
    const _Float16* __restrict__ Qr, const _Float16* __restrict__ Kr,
    const _Float16* __restrict__ VtG,
    const float* __restrict__ qs, const float* __restrict__ ks,
    float* __restrict__ PartA, float* __restrict__ PartB,
    float* __restrict__ psA, float* __restrict__ psB,
    _Float16* __restrict__ Ao) {
  __shared__ _Float16 Ks[KVB * 128];   // 16KB, XOR-swizzled content
  __shared__ _Float16 Vs[128 * KVB];   // 16KB

  const int tid = threadIdx.x;
  const int w = tid >> 6;
  const int l = tid & 63;
  const int l31 = l & 31;
  const int hi = l >> 5;
  const int sw7 = (l31 & 7) << 4;
  const int bu = blockIdx.x;
  const int b = bu >> 4, u = bu & 15;
  const int kvh = u >> 2;

  const int task = g_tasks[blockIdx.y];
  const int heavy = task & 1;
  const int half = (task >> 1) & 1;
  const int qt = task >> 2;
  const int q0 = qt * 128;
  const int halfLen = qt + 1;
  const int t0 = heavy ? half * halfLen : 0;
  const int t1 = heavy ? t0 + halfLen : 2 * qt + 2;

  float ma = fmaxf(fabsf(qs[l]), fabsf(qs[l + 64]));
  float mb = fmaxf(fabsf(ks[l]), fabsf(ks[l + 64]));
  #pragma unroll
  for (int d = 1; d < 64; d <<= 1) {
    ma = fmaxf(ma, __shfl_xor(ma, d));
    mb = fmaxf(mb, __shfl_xor(mb, d));
  }
  const float M2 = 1.4426950408889634f * ma * mb;
  const float K2 = 0.12752982260735795f; // log2(e)/sqrt(128)

  const _Float16* Kbase = Kr + (size_t)(b * NKV + kvh) * SS * HH;
  const _Float16* Vbase = VtG + (size_t)(b * NKV + kvh) * HH * SS;

  f16x8 qf[8];
  {
    const _Float16* qp = Qr + ((size_t)(b * NQ + u) * SS + q0 + w * 32 + l31) * HH + hi * 8;
    #pragma unroll
    for (int hs = 0; hs < 8; hs++) {
      qf[hs] = *(const f16x8*)(qp + hs * 16);
      qf[hs] *= (_Float16)K2;
    }
  }

  f32x16 acc0 = {}, acc1 = {}, acc2 = {}, acc3 = {};
  float psum = 0.f;

  auto stage = [&](int t) {
    const int kv0 = t * KVB;
    #pragma unroll
    for (int it = 0; it < 4; it++) {
      const int n = it * 256 + tid;
      {
        const int row = n >> 4, c = n & 15;
        const int cs = c ^ (row & 7);
        gll16(Kbase + (size_t)(kv0 + row) * HH + cs * 8,
              &Ks[(size_t)(it * 256 + w * 64) * 8]);
      }
      {
        const int row = n >> 3, c = n & 7;
        const int cs = c ^ (row & 7);
        gll16(Vbase + (size_t)row * SS + kv0 + cs * 8,
              &Vs[(size_t)(it * 256 + w * 64) * 8]);
      }
    }
  };

  const int qwb = q0 + w * 32;
  const int qlane = qwb + l31;

  for (int t = t0; t < t1; t++) {
    stage(t);
    __syncthreads();
    const int kv0 = t * KVB;
    if (kv0 <= qwb + 31) {
      const char* Kb = (const char*)&Ks[0];
      const char* Vb = (const char*)&Vs[0];

      f32x16 S0 = {}, S1 = {};
      __builtin_amdgcn_s_setprio(1);
      #pragma unroll
      for (int hs = 0; hs < 8; hs++) {
        const int ch = hs * 2 + hi;
        f16x8 k0 = *(const f16x8*)(Kb + l31 * 256 + ((ch << 4) ^ sw7));
        f16x8 k1 = *(const f16x8*)(Kb + (32 + l31) * 256 + ((ch << 4) ^ sw7));
        S0 = __builtin_amdgcn_mfma_f32_32x32x16_f16(k0, qf[hs], S0, 0, 0, 0);
        S1 = __builtin_amdgcn_mfma_f32_32x32x16_f16(k1, qf[hs], S1, 0, 0, 0);
      }
      __builtin_amdgcn_s_setprio(0);

      const bool domask = (kv0 + 63 > qwb);
      float p0[16], p1[16];
      #pragma unroll
      for (int r = 0; r < 16; r++) {
        const int cr = (r & 3) + 8 * (r >> 2) + 4 * hi;
        float e0 = fexp2(S0[r] - M2);
        float e1 = fexp2(S1[r] - M2);
        if (domask) {
          if (kv0 + cr > qlane) e0 = 0.f;
          if (kv0 + 32 + cr > qlane) e1 = 0.f;
        }
        p0[r] = e0; p1[r] = e1;
        psum += e0 + e1;
      }

      unsigned int pkv[4][4];
      #pragma unroll
      for (int g = 0; g < 4; g++) {
        pkv[0][g] = pkrtz(p0[2 * g], p0[2 * g + 1]);
        pkv[1][g] = pkrtz(p0[8 + 2 * g], p0[9 + 2 * g]);
        pkv[2][g] = pkrtz(p1[2 * g], p1[2 * g + 1]);
        pkv[3][g] = pkrtz(p1[8 + 2 * g], p1[9 + 2 * g]);
      }
      f16x8 pa[4];
      #pragma unroll
      for (int ksx = 0; ksx < 4; ksx++) {
        unsigned int a0 = pkv[ksx][0], a1 = pkv[ksx][1], a2 = pkv[ksx][2], a3 = pkv[ksx][3];
        unsigned int x0 = (unsigned int)__shfl_xor((int)a0, 32);
        unsigned int x1 = (unsigned int)__shfl_xor((int)a1, 32);
        unsigned int x2 = (unsigned int)__shfl_xor((int)a2, 32);
        unsigned int x3 = (unsigned int)__shfl_xor((int)a3, 32);
        uint4v dv;
        dv.x = hi ? x2 : a0;
        dv.y = hi ? x3 : a1;
        dv.z = hi ? a2 : x0;
        dv.w = hi ? a3 : x1;
        pa[ksx] = __builtin_bit_cast(f16x8, dv);
      }

      __builtin_amdgcn_s_setprio(1);
      #pragma unroll
      for (int ksx = 0; ksx < 4; ksx++) {
        const int ch = ksx * 2 + hi;
        f16x8 v0 = *(const f16x8*)(Vb + (0 * 32 + l31) * 128 + ((ch << 4) ^ sw7));
        acc0 = __builtin_amdgcn_mfma_f32_32x32x16_f16(pa[ksx], v0, acc0, 0, 0, 0);
        f16x8 v1 = *(const f16x8*)(Vb + (1 * 32 + l31) * 128 + ((ch << 4) ^ sw7));
        acc1 = __builtin_amdgcn_mfma_f32_32x32x16_f16(pa[ksx], v1, acc1, 0, 0, 0);
        f16x8 v2 = *(const f16x8*)(Vb + (2 * 32 + l31) * 128 + ((ch << 4) ^ sw7));
        acc2 = __builtin_amdgcn_mfma_f32_32x32x16_f16(pa[ksx], v2, acc2, 0, 0, 0);
        f16x8 v3 = *(const f16x8*)(Vb + (3 * 32 + l31) * 128 + ((ch << 4) ^ sw7));
        acc3 = __builtin_amdgcn_mfma_f32_32x32x16_f16(pa[ksx], v3, acc3, 0, 0, 0);
      }
      __builtin_amdgcn_s_setprio(0);
    }
    __syncthreads();
  }

  const float tot = psum + __shfl_xor(psum, 32);
  if (heavy) {
    const int slot = bu * 8 + (qt - 8);
    float* pPart = (half ? PartB : PartA) + (size_t)slot * 16384;
    float* sPart = (half ? psB : psA) + slot * 128;
    if (hi == 0) sPart[w * 32 + l31] = tot;
    #pragma unroll
    for (int r = 0; r < 16; r++) {
      const int cr = (r & 3) + 8 * (r >> 2) + 4 * hi;
      float* dst = pPart + (size_t)(w * 32 + cr) * 128 + l31;
      dst[0]  = acc0[r];
      dst[32] = acc1[r];
      dst[64] = acc2[r];
      dst[96] = acc3[r];
    }
  } else {
    const float inv = 1.f / tot;
    #pragma unroll
    for (int r = 0; r < 16; r++) {
      const int cr = (r & 3) + 8 * (r >> 2) + 4 * hi;
      const float ivr = __shfl(inv, cr);
      _Float16* dst = Ao + ((size_t)(b * SS + q0 + w * 32 + cr)) * MM + u * HH + l31;
      dst[0]  = (_Float16)(acc0[r] * ivr);
      dst[32] = (_Float16)(acc1[r] * ivr);
      dst[64] = (_Float16)(acc2[r] * ivr);
      dst[96] = (_Float16)(acc3[r] * ivr);
    }
  }
}

// ---------------- combine heavy-strip partials -> Ao f16 ----------------
__global__ __launch_bounds__(256) void k_fin(
    const float* __restrict__ PartA, const float* __restrict__ PartB,
    const float* __restrict__ psA, const float* __restrict__ psB,
    _Float16* __restrict__ Ao) {
  const int slot = blockIdx.x;
  const int bu = slot >> 3, st = slot & 7;
  const int b = bu >> 4, u = bu & 15;
  const int qt = st + 8;
  const float* pa = PartA + (size_t)slot * 16384;
  const float* pb = PartB + (size_t)slot * 16384;
  const float* sa = psA + slot * 128;
  const float* sb = psB + slot * 128;
  #pragma unroll
  for (int it = 0; it < 16; it++) {
    const int unit = it * 256 + threadIdx.x;
    const int qr = unit >> 5, cg = unit & 31;
    const float inv = 1.f / (sa[qr] + sb[qr]);
    f32x4 va = *(const f32x4*)(pa + qr * 128 + cg * 4);
    f32x4 vb = *(const f32x4*)(pb + qr * 128 + cg * 4);
    f16x4 o = { (_Float16)((va[0] + vb[0]) * inv), (_Float16)((va[1] + vb[1]) * inv),
                (_Float16)((va[2] + vb[2]) * inv), (_Float16)((va[3] + vb[3]) * inv) };
    *(f16x4*)(Ao + ((size_t)(b * SS + qt * 128 + qr)) * MM + u * HH + cg * 4) = o;
  }
}

// ---------------- launcher ----------------
extern "C" void kernel_launch(void* const* d_in, const int* in_sizes, int n_in,
                              void* d_out, int out_size, void* d_ws, size_t ws_size,
                              hipStream_t stream) {
  const float* hidden = (const float*)d_in[0];
  const float* Wq = (const float*)d_in[2];
  const float* Wk = (const float*)d_in[3];
  const float* Wv = (const float*)d_in[4];
  const float* Wo = (const float*)d_in[5];
  const float* q_scale = (const float*)d_in[6];
  const float* k_scale = (const float*)d_in[7];

  char* ws = (char*)d_ws;
  _Float16* Xb    = (_Float16*)(ws);               // 4096x2048      16.78 MB (dead after GEMM1)
  _Float16* Wqkvt = (_Float16*)(ws + 16777216);    // 3072x2048      12.58 MB
  _Float16* Wot   = (_Float16*)(ws + 29360128);    // 2048x2048       8.39 MB
  _Float16* qkv   = (_Float16*)(ws + 37748736);    // 4096x3072      25.17 MB (dead after vtrans)
  _Float16* Qr    = (_Float16*)(ws + 62914560);    // 2x16x2048x128  16.78 MB
  _Float16* Kr    = (_Float16*)(ws + 79691776);    // 2x4x2048x128    4.19 MB
  _Float16* VtG   = (_Float16*)(ws + 83886080);    // 2x4x128x2048    4.19 MB
  _Float16* Ao    = (_Float16*)(ws + 88080384);    // 4096x2048      16.78 MB
  float*    PartB = (float*)(ws);                  // over Xb
  float*    PartA = (float*)(ws + 37748736);       // over qkv
  float*    psA   = (float*)(ws + 54525952);       // 128 KB
  float*    psB   = (float*)(ws + 54657024);       // 128 KB

  k_f32_to_f16<<<dim3(8192), dim3(256), 0, stream>>>(hidden, Xb, 2097152);
  k_wtrans<<<dim3(64, 64, 4), dim3(256), 0, stream>>>(Wq, Wk, Wv, Wo, Wqkvt, Wot);
  k_gemm256<3, true><<<dim3(256), dim3(512), 0, stream>>>(Xb, Wqkvt, (void*)qkv, 16, 3072, 2048);
  k_normrope<<<dim3(4096, 5), dim3(256), 0, stream>>>(qkv, q_scale, k_scale, Qr, Kr);
  k_vtrans<<<dim3(64, 32), dim3(256), 0, stream>>>(qkv, VtG);
  k_attn<<<dim3(32, 24), dim3(256), 0, stream>>>(Qr, Kr, VtG, q_scale, k_scale,
                                                 PartA, PartB, psA, psB, Ao);
  k_fin<<<dim3(256), dim3(256), 0, stream>>>(PartA, PartB, psA, psB, Ao);
  k_gemm256<2, false><<<dim3(256), dim3(512), 0, stream>>>(Ao, Wot, d_out, 16, 2048, 2048);
}